// Round 9
// baseline (927.400 us; speedup 1.0000x reference)
//
#include <hip/hip_runtime.h>
#include <hip/hip_bf16.h>
#include <math.h>

typedef __bf16 bf16_t;
typedef __attribute__((ext_vector_type(8))) __bf16 bf16x8;
typedef __attribute__((ext_vector_type(4))) __bf16 bf16x4;
typedef __attribute__((ext_vector_type(4))) float f32x4;
typedef __attribute__((ext_vector_type(16))) float f32x16;

#define NTOK 8192   // B*T
#define HDIM 1024
#define DFF  4096
#define RHID 512

__device__ __forceinline__ float gelu_exact(float v) {
  return 0.5f * v * (1.0f + erff(v * 0.70710678118654752f));
}

// tanh-form gelu via sigmoid; max abs err ~3e-4 (noise vs bf16 quantization).
__device__ __forceinline__ float gelu_fast(float v) {
  const float g = 1.5957691216057308f * (v + 0.044715f * v * v * v);
  return v / (1.0f + __expf(-g));
}

__device__ __forceinline__ void async_cp16(void* lds, const void* g) {
  __builtin_amdgcn_global_load_lds(
      (__attribute__((address_space(1))) void*)g,
      (__attribute__((address_space(3))) void*)lds, 16, 0, 0);
}

// XCD-aware remap for FULL launches: blocks round-robin XCDs on g&7; each
// XCD owns an 8-mt strip (A-strip L2-resident), mt fastest for B reuse.
__device__ __forceinline__ void remap_tile(int g, int& mt, int& nt) {
  mt = ((g & 7) << 3) | ((g >> 3) & 7);
  nt = g >> 6;
}

// ---------------------------------------------------------------------------
// GEMM tile 128x128, BK=64 single-buffered (r0-proven sync structure),
// 4 waves 2x2, per-wave 64x64 as 2x2 of 32x32x16 MFMA (half the MFMA
// instructions of the 16x16x32 form at the same FLOPs; higher ceiling).
// A-frag: row=lane&31, k=(lane>>5)*8+j. C/D: col=lane&31,
// row=(r&3)+8*(r>>2)+4*(lane>>5), r in [0,16)  [m74/m101-verified layout].
// LDS layout + rotation swizzle identical to r5 (slot=(ksl+row)&7).
// MODE 0: h = bf16(gelu_fast(C)) -> Hout.    [COMPACT: A rows gathered]
// MODE 1: x = C; hi/lo bf16 split.
// MODE 2: x = w*C + (1-w)*(hi+lo); hi/lo stored.
//   WRITE_OUT: also Xout = v (final iter, survivors).
//   HALTW: rows with Stil[tok]==0 get Xout = (float)hi+(float)lo (== the
//          baseline's w=0 blend output).
//   COMPACT (MODE2): A rows compact-direct; Xb/Xlo/Wmix/Xout token-indexed
//          via ordered idxl; stores guarded to gm < cnt.
// ---------------------------------------------------------------------------
template<int MODE, bool WRITE_OUT, bool HALTW, bool COMPACT>
__device__ __forceinline__ void body_tile(
    int mt, int nt,
    const bf16_t* __restrict__ A, const bf16_t* __restrict__ Bt,
    const float* __restrict__ bias, int N, int K,
    bf16_t* __restrict__ Hout, float* __restrict__ Xout,
    bf16_t* __restrict__ Xb, bf16_t* __restrict__ Xlo,
    const float* __restrict__ Wmix, const float* __restrict__ Stil,
    const int* __restrict__ idxl, int cnt,
    bf16_t* As, bf16_t* Bs)
{
  const int tid  = threadIdx.x;
  const int lane = tid & 63;
  const int wv   = tid >> 6;
  const int wm   = wv >> 1;
  const int wn   = wv & 1;
  const int l31  = lane & 31;
  const int hi2  = lane >> 5;        // 0..1
  const int m0 = mt * 128;
  const int n0 = nt * 128;

  f32x16 acc[2][2];
#pragma unroll
  for (int i = 0; i < 2; ++i)
#pragma unroll
    for (int j = 0; j < 2; ++j)
#pragma unroll
      for (int r = 0; r < 16; ++r)
        acc[i][j][r] = 0.f;

  const int c   = tid;
  const int row = c >> 3;
  const int ks  = (((c & 7) - (row & 7)) & 7) * 8;
  const bf16_t* Ag[4];
#pragma unroll
  for (int t = 0; t < 4; ++t) {
    int rr = m0 + row + 32 * t;
    if (COMPACT && MODE == 0) rr = idxl[rr < cnt ? rr : cnt - 1];
    Ag[t] = A + (size_t)rr * K + ks;
  }
  const bf16_t* Bgb = Bt + (size_t)(n0 + row) * K + ks;
  char* lAb = (char*)As + c * 16;
  char* lBb = (char*)Bs + c * 16;

  for (int kb = 0; kb < K; kb += 64) {
    __syncthreads();
#pragma unroll
    for (int t = 0; t < 4; ++t)
      async_cp16(lAb + 4096 * t, Ag[t] + kb);
#pragma unroll
    for (int t = 0; t < 4; ++t)
      async_cp16(lBb + 4096 * t, Bgb + (size_t)32 * t * K + kb);
    __syncthreads();
#pragma unroll
    for (int kk = 0; kk < 4; ++kk) {
      const int ksl = kk * 2 + hi2;   // k-slot 0..7 (8 bf16 each)
      bf16x8 af[2], bfr[2];
#pragma unroll
      for (int i = 0; i < 2; ++i) {
        const int ra = wm * 64 + i * 32 + l31;
        af[i] = *(const bf16x8*)&As[ra * 64 + ((ksl + ra) & 7) * 8];
      }
#pragma unroll
      for (int j = 0; j < 2; ++j) {
        const int rb = wn * 64 + j * 32 + l31;
        bfr[j] = *(const bf16x8*)&Bs[rb * 64 + ((ksl + rb) & 7) * 8];
      }
#pragma unroll
      for (int i = 0; i < 2; ++i)
#pragma unroll
        for (int j = 0; j < 2; ++j)
          acc[i][j] = __builtin_amdgcn_mfma_f32_32x32x16_bf16(af[i], bfr[j], acc[i][j], 0, 0, 0);
    }
  }

#pragma unroll
  for (int i = 0; i < 2; ++i) {
#pragma unroll
    for (int r = 0; r < 16; ++r) {
      const int gm = m0 + wm * 64 + i * 32 + (r & 3) + 8 * (r >> 2) + 4 * hi2;
      bool act_row = true;
      int tok = gm;
      if (COMPACT && MODE == 2) {
        act_row = gm < cnt;
        tok = idxl[act_row ? gm : cnt - 1];
      }
      float wmix = 0.f, onemw = 0.f, st = 1.f;
      if (MODE == 2) {
        wmix = Wmix[tok]; onemw = 1.f - wmix;
        if (HALTW) st = Stil[tok];
      }
#pragma unroll
      for (int j = 0; j < 2; ++j) {
        const int gn = n0 + wn * 64 + j * 32 + l31;
        float v = acc[i][j][r] + bias[gn];
        if (MODE == 0) {
          Hout[(size_t)gm * N + gn] = (bf16_t)gelu_fast(v);
        } else {
          const size_t idx = (size_t)tok * N + gn;
          if (MODE == 2) {
            const float xold = (float)Xb[idx] + (float)Xlo[idx];
            v = wmix * v + onemw * xold;
          }
          if (act_row) {
            const bf16_t hh = (bf16_t)v;
            const bf16_t ll = (bf16_t)(v - (float)hh);
            Xb[idx]  = hh;
            Xlo[idx] = ll;
            if (WRITE_OUT) Xout[idx] = v;
            if (HALTW && st == 0.f) Xout[idx] = (float)hh + (float)ll;
          }
        }
      }
    }
  }
}

// ---------------------------------------------------------------------------
// Router tile (hi/lo split ~fp32), BK=32 single-buffered, 32KB LDS, 4 waves.
// UNTOUCHED from r5 (halting-decision numerics must not move).
// COMPACT: A rows (xb/xlo) gathered via ordered idxl; Hr scattered + guarded.
// ---------------------------------------------------------------------------
template<bool COMPACT>
__device__ __forceinline__ void router_tile(
    int mt, int nt,
    const bf16_t* __restrict__ Ah, const bf16_t* __restrict__ Al,
    const bf16_t* __restrict__ Bh, const bf16_t* __restrict__ Bl,
    const float* __restrict__ bias, float* __restrict__ Hr,
    const int* __restrict__ idxl, int cnt,
    bf16_t* Ahs, bf16_t* Als, bf16_t* Bhs, bf16_t* Bls)
{
  const int K = HDIM, N = RHID;
  const int tid  = threadIdx.x;
  const int lane = tid & 63;
  const int wv   = tid >> 6;
  const int wm   = wv >> 1;
  const int wn   = wv & 1;
  const int lr   = lane & 15;
  const int quad = lane >> 4;
  const int m0 = mt * 128;
  const int n0 = nt * 128;

  f32x4 acc[4][4];
#pragma unroll
  for (int i = 0; i < 4; ++i)
#pragma unroll
    for (int j = 0; j < 4; ++j)
      acc[i][j] = (f32x4){0.f, 0.f, 0.f, 0.f};

  const int c0 = tid;
  const int c1 = tid + 256;
  const int r0 = c0 >> 2, r1 = c1 >> 2;
  const int ks0 = ((c0 ^ r0) & 3) * 8;
  const int ks1 = ((c1 ^ r1) & 3) * 8;
  int tr0 = m0 + r0, tr1 = m0 + r1;
  if (COMPACT) {
    tr0 = idxl[tr0 < cnt ? tr0 : cnt - 1];
    tr1 = idxl[tr1 < cnt ? tr1 : cnt - 1];
  }
  const size_t aoff0 = (size_t)tr0 * K + ks0;
  const size_t aoff1 = (size_t)tr1 * K + ks1;
  const size_t boff0 = (size_t)(n0 + r0) * K + ks0;
  const size_t boff1 = (size_t)(n0 + r1) * K + ks1;
  const int sw = ((quad ^ lr) & 3) * 8;

  for (int k0 = 0; k0 < K; k0 += 32) {
    __syncthreads();
    async_cp16((char*)Ahs + c0 * 16, Ah + aoff0 + k0);
    async_cp16((char*)Ahs + c1 * 16, Ah + aoff1 + k0);
    async_cp16((char*)Als + c0 * 16, Al + aoff0 + k0);
    async_cp16((char*)Als + c1 * 16, Al + aoff1 + k0);
    async_cp16((char*)Bhs + c0 * 16, Bh + boff0 + k0);
    async_cp16((char*)Bhs + c1 * 16, Bh + boff1 + k0);
    async_cp16((char*)Bls + c0 * 16, Bl + boff0 + k0);
    async_cp16((char*)Bls + c1 * 16, Bl + boff1 + k0);
    __syncthreads();
    bf16x8 ah[4], al[4], bh[4], bl[4];
#pragma unroll
    for (int i = 0; i < 4; ++i) {
      const int ao = (wm * 64 + i * 16 + lr) * 32 + sw;
      ah[i] = *(const bf16x8*)&Ahs[ao];
      al[i] = *(const bf16x8*)&Als[ao];
    }
#pragma unroll
    for (int j = 0; j < 4; ++j) {
      const int bo = (wn * 64 + j * 16 + lr) * 32 + sw;
      bh[j] = *(const bf16x8*)&Bhs[bo];
      bl[j] = *(const bf16x8*)&Bls[bo];
    }
#pragma unroll
    for (int i = 0; i < 4; ++i)
#pragma unroll
      for (int j = 0; j < 4; ++j) {
        acc[i][j] = __builtin_amdgcn_mfma_f32_16x16x32_bf16(ah[i], bh[j], acc[i][j], 0, 0, 0);
        acc[i][j] = __builtin_amdgcn_mfma_f32_16x16x32_bf16(al[i], bh[j], acc[i][j], 0, 0, 0);
        acc[i][j] = __builtin_amdgcn_mfma_f32_16x16x32_bf16(ah[i], bl[j], acc[i][j], 0, 0, 0);
      }
  }

#pragma unroll
  for (int i = 0; i < 4; ++i)
#pragma unroll
    for (int r = 0; r < 4; ++r) {
      const int gm = m0 + wm * 64 + i * 16 + quad * 4 + r;
      bool act_row = true;
      int tok = gm;
      if (COMPACT) {
        act_row = gm < cnt;
        tok = idxl[act_row ? gm : cnt - 1];
      }
#pragma unroll
      for (int j = 0; j < 4; ++j) {
        const int gn = n0 + wn * 64 + j * 16 + lr;
        if (act_row) Hr[(size_t)tok * N + gn] = gelu_exact(acc[i][j][r] + bias[gn]);
      }
    }
}

// MODE1/MODE2 standalone GEMM, 128x128 tiles, 32KB LDS.
// COMPACT: active tiles remapped to CONTIGUOUS blockIdx (all XCDs busy).
template<int MODE, bool WRITE_OUT, bool HALTW, bool COMPACT>
__global__ __launch_bounds__(256, 4)
void k_gemm(const bf16_t* __restrict__ A, const bf16_t* __restrict__ Bt,
            const float* __restrict__ bias, int N, int K,
            float* __restrict__ Xout, bf16_t* __restrict__ Xb,
            bf16_t* __restrict__ Xlo, const float* __restrict__ Wmix,
            const float* __restrict__ Stil,
            const int* __restrict__ idxl, const int* __restrict__ cntp)
{
  __shared__ __align__(16) bf16_t sm[16384];
  int cnt = NTOK;
  int mt, nt;
  if (COMPACT) {
    cnt = *cntp;
    const int mtA = (cnt + 127) >> 7;
    if ((int)blockIdx.x >= mtA * (N >> 7)) return;
    mt = blockIdx.x % mtA;
    nt = blockIdx.x / mtA;
  } else {
    remap_tile(blockIdx.x, mt, nt);
  }
  body_tile<MODE, WRITE_OUT, HALTW, COMPACT>(
      mt, nt, A, Bt, bias, N, K, nullptr, Xout, Xb, Xlo, Wmix, Stil,
      idxl, cnt, sm, sm + 8192);
}

// MODE0 body 128x128 tiles (2048 blocks) + optional fused router tail (256).
// COMPACT: active tiles contiguous (mt = g % mtA) so work round-robins XCDs.
template<bool COMPACT>
__global__ __launch_bounds__(256, 4)
void k_body0_router(const bf16_t* __restrict__ xb, const bf16_t* __restrict__ W1t,
                    const float* __restrict__ bb1, bf16_t* __restrict__ hbuf,
                    const bf16_t* __restrict__ xlo,
                    const bf16_t* __restrict__ R1h, const bf16_t* __restrict__ R1l,
                    const float* __restrict__ Rb1, float* __restrict__ hr,
                    const int* __restrict__ idxl, const int* __restrict__ cntp,
                    int nbody)
{
  __shared__ __align__(16) bf16_t sm[16384];
  int cnt = NTOK;
  int mtA = NTOK >> 7;
  if (COMPACT) {
    cnt = *cntp;
    mtA = (cnt + 127) >> 7;
  }
  const int g = blockIdx.x;
  if (g < nbody) {
    int mt, nt;
    if (COMPACT) {
      if (g >= mtA * (DFF >> 7)) return;
      mt = g % mtA;
      nt = g / mtA;
    } else {
      remap_tile(g, mt, nt);
    }
    body_tile<0, false, false, COMPACT>(
        mt, nt, xb, W1t, bb1, DFF, HDIM, hbuf,
        nullptr, nullptr, nullptr, nullptr, nullptr,
        idxl, cnt, sm, sm + 8192);
  } else {
    const int g2 = g - nbody;
    int mt, nt;
    if (COMPACT) {
      if (g2 >= mtA * (RHID >> 7)) return;
      mt = g2 % mtA;
      nt = g2 / mtA;
    } else {
      remap_tile(g2, mt, nt);
    }
    router_tile<COMPACT>(mt, nt, xb, xlo, R1h, R1l, Rb1, hr, idxl, cnt,
                         sm, sm + 4096, sm + 8192, sm + 12288);
  }
}

// ---------------------------------------------------------------------------
// ACT: one wave per token, fp32 logit + exact halting update (in-place state).
// ---------------------------------------------------------------------------
__global__ void act_kernel(const float* __restrict__ Hr,
                           const float* __restrict__ rw2, const float* __restrict__ rb2,
                           float* __restrict__ cum_p, float* __restrict__ still_r,
                           float* __restrict__ wsum, float* __restrict__ wvec)
{
  const int t = blockIdx.x * 4 + (threadIdx.x >> 6);
  const int lane = threadIdx.x & 63;
  float s = 0.f;
#pragma unroll
  for (int j = 0; j < 8; ++j) {
    const int m = lane + j * 64;
    s += Hr[(size_t)t * RHID + m] * rw2[m];
  }
  for (int off = 32; off > 0; off >>= 1) s += __shfl_down(s, off, 64);
  if (lane == 0) {
    const float logit = s + rb2[0];
    const float p = 1.f / (1.f + expf(-logit));
    const float cum = cum_p[t];
    const float still = still_r[t];
    const float rem = fmaxf(1.f - cum, 0.f);
    const bool halt = (cum + p) >= 0.99f;
    const float w = (halt ? rem : p) * still;
    wvec[t] = w;
    wsum[t] += w;
    cum_p[t] = cum + w;
    if (halt) still_r[t] = 0.f;
  }
}

// ---------------------------------------------------------------------------
// Ordered survivor compaction: token-sorted idxl (sequential gathers) via
// single-block ballot/popc prefix scan. ~5 us.
// ---------------------------------------------------------------------------
__global__ void compact_kernel(const float* __restrict__ still,
                               int* __restrict__ idxl, int* __restrict__ cntp)
{
  __shared__ int wsumS[16];
  const int tid  = threadIdx.x;     // 0..1023
  const int w    = tid >> 6;
  const int lane = tid & 63;
  int base = 0;
  for (int c = 0; c < 8; ++c) {
    const int t = c * 1024 + tid;
    const bool f = still[t] > 0.f;
    const unsigned long long m = __ballot(f);
    if (lane == 0) wsumS[w] = __popcll(m);
    __syncthreads();
    int woff = 0, tot = 0;
#pragma unroll
    for (int i = 0; i < 16; ++i) {
      const int v = wsumS[i];
      if (i < w) woff += v;
      tot += v;
    }
    if (f) idxl[base + woff + __popcll(m & ((1ull << lane) - 1ull))] = t;
    base += tot;
    __syncthreads();
  }
  if (tid == 0) *cntp = base;
}

// ---------------------------------------------------------------------------
// Fused prep: Wb1/Wb2/Rw1 transposes + x->bf16 convert + ACT state init.
// ---------------------------------------------------------------------------
__device__ __forceinline__ void transpose_tile(
    const float* __restrict__ src, int srcld, int dstld,
    bf16_t* __restrict__ dst, bf16_t* __restrict__ dlo,
    int bx, int by, float* tile /* 32x33 */)
{
  const int tx = threadIdx.x & 31;
  const int ty = threadIdx.x >> 5;
#pragma unroll
  for (int l = 0; l < 4; ++l)
    tile[(ty + l * 8) * 33 + tx] = src[(size_t)(by * 32 + ty + l * 8) * srcld + bx * 32 + tx];
  __syncthreads();
#pragma unroll
  for (int l = 0; l < 4; ++l) {
    const int c = bx * 32 + ty + l * 8;
    const int r = by * 32 + tx;
    const float v = tile[tx * 33 + ty + l * 8];
    const bf16_t hi = (bf16_t)v;
    dst[(size_t)c * dstld + r] = hi;
    if (dlo) dlo[(size_t)c * dstld + r] = (bf16_t)(v - (float)hi);
  }
}

__global__ void prep_kernel(const float* __restrict__ x,
                            const float* __restrict__ Wb1,
                            const float* __restrict__ Wb2,
                            const float* __restrict__ Rw1,
                            bf16_t* __restrict__ xb,
                            bf16_t* __restrict__ W1t, bf16_t* __restrict__ W2t,
                            bf16_t* __restrict__ R1h, bf16_t* __restrict__ R1l,
                            float* __restrict__ cum0, float* __restrict__ stil0,
                            float* __restrict__ wsum0, int* __restrict__ cntp)
{
  __shared__ float tile[32 * 33];
  const int g = blockIdx.x;
  if (g < 4096) {                       // Wb1 (H x DFF) -> W1t (DFF x H)
    transpose_tile(Wb1, DFF, HDIM, W1t, nullptr, g & 127, g >> 7, tile);
  } else if (g < 8192) {                // Wb2 (DFF x H) -> W2t (H x DFF)
    const int g2 = g - 4096;
    transpose_tile(Wb2, HDIM, DFF, W2t, nullptr, g2 & 31, g2 >> 5, tile);
  } else if (g < 9728) {                // Rw1[i] (first 1024 of 1025 rows) -> hi/lo
    const int g3 = g - 8192;
    const int i  = g3 >> 9;
    const int r  = g3 & 511;
    transpose_tile(Rw1 + (size_t)i * 1025 * RHID, RHID, HDIM,
                   R1h + (size_t)i * RHID * HDIM, R1l + (size_t)i * RHID * HDIM,
                   r & 15, r >> 4, tile);
  } else if (g < 17920) {               // x fp32 -> xb bf16 (vectorized)
    const int i = (g - 9728) * 256 + threadIdx.x;
    const float4 v = ((const float4*)x)[i];
    bf16x4 hb;
    hb[0] = (bf16_t)v.x; hb[1] = (bf16_t)v.y; hb[2] = (bf16_t)v.z; hb[3] = (bf16_t)v.w;
    ((bf16x4*)xb)[i] = hb;
  } else {                              // ACT state init
    const int t = (g - 17920) * 256 + threadIdx.x;
    cum0[t] = 0.f; stil0[t] = 1.f; wsum0[t] = 1.f;
    if (t == 0) *cntp = 0;
  }
}

__global__ void finalize_kernel(const float* __restrict__ wsum, float* __restrict__ out)
{
  __shared__ float red[256];
  float s = 0.f;
  for (int i = threadIdx.x; i < NTOK; i += 256) s += wsum[i];
  red[threadIdx.x] = s;
  __syncthreads();
  for (int o = 128; o > 0; o >>= 1) {
    if (threadIdx.x < o) red[threadIdx.x] += red[threadIdx.x + o];
    __syncthreads();
  }
  if (threadIdx.x == 0) {
    const float avg = red[0] / (float)NTOK;
    float d = avg - 2.5f;
    d = fmaxf(d, 0.f);
    out[0] = 0.01f * d * d;
  }
}

extern "C" void kernel_launch(void* const* d_in, const int* in_sizes, int n_in,
                              void* d_out, int out_size, void* d_ws, size_t ws_size,
                              hipStream_t stream) {
  const float* x   = (const float*)d_in[0];
  const float* Wb1 = (const float*)d_in[1];
  const float* bb1 = (const float*)d_in[2];
  const float* Wb2 = (const float*)d_in[3];
  const float* bb2 = (const float*)d_in[4];
  const float* Rw1 = (const float*)d_in[5];  // (3, 1025, 512)
  const float* Rb1 = (const float*)d_in[6];  // (3, 512)
  const float* Rw2 = (const float*)d_in[7];  // (3, 512)
  const float* Rb2 = (const float*)d_in[8];  // (3,)
  float* out = (float*)d_out;

  char* ws = (char*)d_ws;
  size_t off = 0;
  auto carve = [&](size_t bytes) -> void* {
    void* p = ws + off;
    off += (bytes + 255) & ~(size_t)255;
    return p;
  };
  bf16_t* xb   = (bf16_t*)carve((size_t)NTOK * HDIM * 2);
  bf16_t* xlo  = (bf16_t*)carve((size_t)NTOK * HDIM * 2);
  bf16_t* hbuf = (bf16_t*)carve((size_t)NTOK * DFF * 2);
  bf16_t* W1t  = (bf16_t*)carve((size_t)HDIM * DFF * 2);
  bf16_t* W2t  = (bf16_t*)carve((size_t)HDIM * DFF * 2);
  bf16_t* R1h  = (bf16_t*)carve((size_t)3 * RHID * HDIM * 2);
  bf16_t* R1l  = (bf16_t*)carve((size_t)3 * RHID * HDIM * 2);
  float*  hr   = (float*)carve((size_t)NTOK * RHID * 4);
  float*  cum  = (float*)carve((size_t)NTOK * 4);
  float*  stil = (float*)carve((size_t)NTOK * 4);
  float*  wsum = (float*)carve((size_t)NTOK * 4);
  float*  wvec = (float*)carve((size_t)NTOK * 4);
  int*    idxl = (int*)carve((size_t)NTOK * 4);
  int*    cntp = (int*)carve(256);

  prep_kernel<<<17952, 256, 0, stream>>>(x, Wb1, Wb2, Rw1, xb, W1t, W2t,
                                         R1h, R1l, cum, stil, wsum, cntp);

  // mandatory first body: x = body(x); x kept as hi/lo bf16 pair
  k_body0_router<false><<<2048, 256, 0, stream>>>(
      xb, W1t, bb1, hbuf, xlo, nullptr, nullptr, nullptr, nullptr,
      idxl, cntp, 2048);
  k_gemm<1, false, false, false><<<512, 256, 0, stream>>>(
      hbuf, W2t, bb2, HDIM, DFF, nullptr, xb, xlo, nullptr, nullptr,
      idxl, cntp);

  // i = 0: full
  k_body0_router<false><<<2048 + 256, 256, 0, stream>>>(
      xb, W1t, bb1, hbuf, xlo, R1h, R1l, Rb1, hr, idxl, cntp, 2048);
  act_kernel<<<2048, 256, 0, stream>>>(hr, Rw2, Rb2, cum, stil, wsum, wvec);
  k_gemm<2, false, false, false><<<512, 256, 0, stream>>>(
      hbuf, W2t, bb2, HDIM, DFF, nullptr, xb, xlo, wvec, nullptr,
      idxl, cntp);

  // i = 1: full; afterwards still_r marks survivors of iterations 0+1
  k_body0_router<false><<<2048 + 256, 256, 0, stream>>>(
      xb, W1t, bb1, hbuf, xlo,
      R1h + (size_t)RHID * HDIM, R1l + (size_t)RHID * HDIM,
      Rb1 + RHID, hr, idxl, cntp, 2048);
  act_kernel<<<2048, 256, 0, stream>>>(hr, Rw2 + RHID, Rb2 + 1,
                                       cum, stil, wsum, wvec);
  compact_kernel<<<1, 1024, 0, stream>>>(stil, idxl, cntp);
  // i=1 blend; HALTW writes final Xout for halted tokens (== w=0 blend)
  k_gemm<2, false, true, false><<<512, 256, 0, stream>>>(
      hbuf, W2t, bb2, HDIM, DFF, out, xb, xlo, wvec, stil, idxl, cntp);

  // i = 2: compacted (survivors only; active tiles contiguous across XCDs)
  k_body0_router<true><<<2048 + 256, 256, 0, stream>>>(
      xb, W1t, bb1, hbuf, xlo,
      R1h + (size_t)2 * RHID * HDIM, R1l + (size_t)2 * RHID * HDIM,
      Rb1 + 2 * RHID, hr, idxl, cntp, 2048);
  act_kernel<<<2048, 256, 0, stream>>>(hr, Rw2 + 2 * RHID, Rb2 + 2,
                                       cum, stil, wsum, wvec);
  k_gemm<2, true, false, true><<<512, 256, 0, stream>>>(
      hbuf, W2t, bb2, HDIM, DFF, out, xb, xlo, wvec, nullptr, idxl, cntp);

  finalize_kernel<<<1, 256, 0, stream>>>(wsum, out + (size_t)NTOK * HDIM);
  (void)in_sizes; (void)n_in; (void)out_size; (void)ws_size;
}

// Round 10
// 831.792 us; speedup vs baseline: 1.1149x; 1.1149x over previous
//
#include <hip/hip_runtime.h>
#include <hip/hip_bf16.h>
#include <math.h>

typedef __bf16 bf16_t;
typedef __attribute__((ext_vector_type(8))) __bf16 bf16x8;
typedef __attribute__((ext_vector_type(4))) __bf16 bf16x4;
typedef __attribute__((ext_vector_type(4))) float f32x4;

#define NTOK 8192   // B*T
#define HDIM 1024
#define DFF  4096
#define RHID 512

__device__ __forceinline__ float gelu_exact(float v) {
  return 0.5f * v * (1.0f + erff(v * 0.70710678118654752f));
}

// tanh-form gelu via sigmoid; max abs err ~3e-4 (noise vs bf16 quantization).
__device__ __forceinline__ float gelu_fast(float v) {
  const float g = 1.5957691216057308f * (v + 0.044715f * v * v * v);
  return v / (1.0f + __expf(-g));
}

__device__ __forceinline__ void async_cp16(void* lds, const void* g) {
  __builtin_amdgcn_global_load_lds(
      (__attribute__((address_space(1))) void*)g,
      (__attribute__((address_space(3))) void*)lds, 16, 0, 0);
}

// XCD-aware remap for FULL launches: blocks round-robin XCDs on g&7; each
// XCD owns an 8-mt strip (A-strip L2-resident), mt fastest for B reuse.
__device__ __forceinline__ void remap_tile(int g, int& mt, int& nt) {
  mt = ((g & 7) << 3) | ((g >> 3) & 7);
  nt = g >> 6;
}

// ---------------------------------------------------------------------------
// GEMM tile, BK=64 single-buffered (r0-proven loop). 4 waves 2x2.
// 16x16x32 MFMA; quad-based LDS read (2-way banks = free, m136).
// [r9 lesson: 32x32 fragment reads are structurally 4-way bank-conflicted
//  under global_load_lds's linear 128B-pitch LDS — do not swap shapes here.]
// MODE 0: h = bf16(gelu_fast(C)) -> Hout.    [COMPACT: A rows gathered]
// MODE 1: x = C; hi/lo bf16 split.
// MODE 2: x = w*C + (1-w)*(hi+lo); hi/lo stored.
//   WRITE_OUT: also Xout = v (final iter, survivors).
//   HALTW: for rows with Stil[tok]==0, Xout = (float)hi+(float)lo — exactly
//          the baseline's later w=0 blend output (bit-identical).
//   COMPACT (MODE2): A rows compact-direct; Xb/Xlo/Wmix/Xout token-indexed
//          via ordered idxl; stores guarded to gm < cnt.
// ---------------------------------------------------------------------------
template<int MODE, bool WRITE_OUT, bool HALTW, int WM, int WN, bool COMPACT>
__device__ __forceinline__ void body_tile(
    int mt, int nt,
    const bf16_t* __restrict__ A, const bf16_t* __restrict__ Bt,
    const float* __restrict__ bias, int N, int K,
    bf16_t* __restrict__ Hout, float* __restrict__ Xout,
    bf16_t* __restrict__ Xb, bf16_t* __restrict__ Xlo,
    const float* __restrict__ Wmix, const float* __restrict__ Stil,
    const int* __restrict__ idxl, int cnt,
    bf16_t* As, bf16_t* Bs)
{
  constexpr int BM  = WM * 32;
  constexpr int BN  = WN * 32;
  constexpr int ACH = BM / 32;
  constexpr int BCH = BN / 32;
  const int tid  = threadIdx.x;
  const int lane = tid & 63;
  const int wv   = tid >> 6;
  const int wm   = wv >> 1;
  const int wn   = wv & 1;
  const int lr   = lane & 15;
  const int quad = lane >> 4;
  const int m0 = mt * BM;
  const int n0 = nt * BN;

  f32x4 acc[WM][WN];
#pragma unroll
  for (int i = 0; i < WM; ++i)
#pragma unroll
    for (int j = 0; j < WN; ++j)
      acc[i][j] = (f32x4){0.f, 0.f, 0.f, 0.f};

  const int c   = tid;
  const int row = c >> 3;
  const int ks  = (((c & 7) - (row & 7)) & 7) * 8;
  const bf16_t* Ag[ACH];
#pragma unroll
  for (int t = 0; t < ACH; ++t) {
    int rr = m0 + row + 32 * t;
    if (COMPACT && MODE == 0) rr = idxl[rr < cnt ? rr : cnt - 1];
    Ag[t] = A + (size_t)rr * K + ks;
  }
  const bf16_t* Bgb = Bt + (size_t)(n0 + row) * K + ks;
  char* lAb = (char*)As + c * 16;
  char* lBb = (char*)Bs + c * 16;

  for (int kb = 0; kb < K; kb += 64) {
    __syncthreads();
#pragma unroll
    for (int t = 0; t < ACH; ++t)
      async_cp16(lAb + 4096 * t, Ag[t] + kb);
#pragma unroll
    for (int t = 0; t < BCH; ++t)
      async_cp16(lBb + 4096 * t, Bgb + (size_t)32 * t * K + kb);
    __syncthreads();
#pragma unroll
    for (int kk = 0; kk < 2; ++kk) {
      const int kg = kk * 4 + quad;
      bf16x8 af[WM], bfr[WN];
#pragma unroll
      for (int i = 0; i < WM; ++i) {
        const int ra = wm * (WM * 16) + i * 16 + lr;
        af[i] = *(const bf16x8*)&As[ra * 64 + ((kg + ra) & 7) * 8];
      }
#pragma unroll
      for (int j = 0; j < WN; ++j) {
        const int rb = wn * (WN * 16) + j * 16 + lr;
        bfr[j] = *(const bf16x8*)&Bs[rb * 64 + ((kg + rb) & 7) * 8];
      }
#pragma unroll
      for (int i = 0; i < WM; ++i)
#pragma unroll
        for (int j = 0; j < WN; ++j)
          acc[i][j] = __builtin_amdgcn_mfma_f32_16x16x32_bf16(af[i], bfr[j], acc[i][j], 0, 0, 0);
    }
  }

#pragma unroll
  for (int i = 0; i < WM; ++i) {
#pragma unroll
    for (int r = 0; r < 4; ++r) {
      const int gm = m0 + wm * (WM * 16) + i * 16 + quad * 4 + r;
      bool act_row = true;
      int tok = gm;
      if (COMPACT && MODE == 2) {
        act_row = gm < cnt;
        tok = idxl[act_row ? gm : cnt - 1];
      }
      float wmix = 0.f, onemw = 0.f, st = 1.f;
      if (MODE == 2) {
        wmix = Wmix[tok]; onemw = 1.f - wmix;
        if (HALTW) st = Stil[tok];
      }
#pragma unroll
      for (int j = 0; j < WN; ++j) {
        const int gn = n0 + wn * (WN * 16) + j * 16 + lr;
        float v = acc[i][j][r] + bias[gn];
        if (MODE == 0) {
          Hout[(size_t)gm * N + gn] = (bf16_t)gelu_fast(v);
        } else {
          const size_t idx = (size_t)tok * N + gn;
          if (MODE == 2) {
            const float xold = (float)Xb[idx] + (float)Xlo[idx];
            v = wmix * v + onemw * xold;
          }
          if (act_row) {
            const bf16_t hi = (bf16_t)v;
            const bf16_t lo = (bf16_t)(v - (float)hi);
            Xb[idx]  = hi;
            Xlo[idx] = lo;
            if (WRITE_OUT) Xout[idx] = v;
            if (HALTW && st == 0.f) Xout[idx] = (float)hi + (float)lo;
          }
        }
      }
    }
  }
}

// ---------------------------------------------------------------------------
// Router tile (hi/lo split ~fp32), BK=32 single-buffered, 32KB LDS.
// COMPACT: A rows (xb/xlo) gathered via ordered idxl; Hr scattered + guarded.
// ---------------------------------------------------------------------------
template<bool COMPACT>
__device__ __forceinline__ void router_tile(
    int mt, int nt,
    const bf16_t* __restrict__ Ah, const bf16_t* __restrict__ Al,
    const bf16_t* __restrict__ Bh, const bf16_t* __restrict__ Bl,
    const float* __restrict__ bias, float* __restrict__ Hr,
    const int* __restrict__ idxl, int cnt,
    bf16_t* Ahs, bf16_t* Als, bf16_t* Bhs, bf16_t* Bls)
{
  const int K = HDIM, N = RHID;
  const int tid  = threadIdx.x;
  const int lane = tid & 63;
  const int wv   = tid >> 6;
  const int wm   = wv >> 1;
  const int wn   = wv & 1;
  const int lr   = lane & 15;
  const int quad = lane >> 4;
  const int m0 = mt * 128;
  const int n0 = nt * 128;

  f32x4 acc[4][4];
#pragma unroll
  for (int i = 0; i < 4; ++i)
#pragma unroll
    for (int j = 0; j < 4; ++j)
      acc[i][j] = (f32x4){0.f, 0.f, 0.f, 0.f};

  const int c0 = tid;
  const int c1 = tid + 256;
  const int r0 = c0 >> 2, r1 = c1 >> 2;
  const int ks0 = ((c0 ^ r0) & 3) * 8;
  const int ks1 = ((c1 ^ r1) & 3) * 8;
  int tr0 = m0 + r0, tr1 = m0 + r1;
  if (COMPACT) {
    tr0 = idxl[tr0 < cnt ? tr0 : cnt - 1];
    tr1 = idxl[tr1 < cnt ? tr1 : cnt - 1];
  }
  const size_t aoff0 = (size_t)tr0 * K + ks0;
  const size_t aoff1 = (size_t)tr1 * K + ks1;
  const size_t boff0 = (size_t)(n0 + r0) * K + ks0;
  const size_t boff1 = (size_t)(n0 + r1) * K + ks1;
  const int sw = ((quad ^ lr) & 3) * 8;

  for (int k0 = 0; k0 < K; k0 += 32) {
    __syncthreads();
    async_cp16((char*)Ahs + c0 * 16, Ah + aoff0 + k0);
    async_cp16((char*)Ahs + c1 * 16, Ah + aoff1 + k0);
    async_cp16((char*)Als + c0 * 16, Al + aoff0 + k0);
    async_cp16((char*)Als + c1 * 16, Al + aoff1 + k0);
    async_cp16((char*)Bhs + c0 * 16, Bh + boff0 + k0);
    async_cp16((char*)Bhs + c1 * 16, Bh + boff1 + k0);
    async_cp16((char*)Bls + c0 * 16, Bl + boff0 + k0);
    async_cp16((char*)Bls + c1 * 16, Bl + boff1 + k0);
    __syncthreads();
    bf16x8 ah[4], al[4], bh[4], bl[4];
#pragma unroll
    for (int i = 0; i < 4; ++i) {
      const int ao = (wm * 64 + i * 16 + lr) * 32 + sw;
      ah[i] = *(const bf16x8*)&Ahs[ao];
      al[i] = *(const bf16x8*)&Als[ao];
    }
#pragma unroll
    for (int j = 0; j < 4; ++j) {
      const int bo = (wn * 64 + j * 16 + lr) * 32 + sw;
      bh[j] = *(const bf16x8*)&Bhs[bo];
      bl[j] = *(const bf16x8*)&Bls[bo];
    }
#pragma unroll
    for (int i = 0; i < 4; ++i)
#pragma unroll
      for (int j = 0; j < 4; ++j) {
        acc[i][j] = __builtin_amdgcn_mfma_f32_16x16x32_bf16(ah[i], bh[j], acc[i][j], 0, 0, 0);
        acc[i][j] = __builtin_amdgcn_mfma_f32_16x16x32_bf16(al[i], bh[j], acc[i][j], 0, 0, 0);
        acc[i][j] = __builtin_amdgcn_mfma_f32_16x16x32_bf16(ah[i], bl[j], acc[i][j], 0, 0, 0);
      }
  }

#pragma unroll
  for (int i = 0; i < 4; ++i)
#pragma unroll
    for (int r = 0; r < 4; ++r) {
      const int gm = m0 + wm * 64 + i * 16 + quad * 4 + r;
      bool act_row = true;
      int tok = gm;
      if (COMPACT) {
        act_row = gm < cnt;
        tok = idxl[act_row ? gm : cnt - 1];
      }
#pragma unroll
      for (int j = 0; j < 4; ++j) {
        const int gn = n0 + wn * 64 + j * 16 + lr;
        if (act_row) Hr[(size_t)tok * N + gn] = gelu_exact(acc[i][j][r] + bias[gn]);
      }
    }
}

// MODE1/MODE2 standalone GEMM, 128x128 tiles, 32KB LDS.
// COMPACT: active tiles remapped to CONTIGUOUS blockIdx (all XCDs busy).
template<int MODE, bool WRITE_OUT, bool HALTW, bool COMPACT>
__global__ __launch_bounds__(256, 4)
void k_gemm(const bf16_t* __restrict__ A, const bf16_t* __restrict__ Bt,
            const float* __restrict__ bias, int N, int K,
            float* __restrict__ Xout, bf16_t* __restrict__ Xb,
            bf16_t* __restrict__ Xlo, const float* __restrict__ Wmix,
            const float* __restrict__ Stil,
            const int* __restrict__ idxl, const int* __restrict__ cntp)
{
  __shared__ __align__(16) bf16_t sm[16384];
  int cnt = NTOK;
  int mt, nt;
  if (COMPACT) {
    cnt = *cntp;
    const int mtA = (cnt + 127) >> 7;
    if ((int)blockIdx.x >= mtA * (N >> 7)) return;
    mt = blockIdx.x % mtA;
    nt = blockIdx.x / mtA;
  } else {
    remap_tile(blockIdx.x, mt, nt);
  }
  body_tile<MODE, WRITE_OUT, HALTW, 4, 4, COMPACT>(
      mt, nt, A, Bt, bias, N, K, nullptr, Xout, Xb, Xlo, Wmix, Stil,
      idxl, cnt, sm, sm + 8192);
}

// MODE0 body 128x128 tiles (2048 blocks) + optional fused router tail (256).
// COMPACT: active tiles contiguous (mt = g % mtA) so work round-robins XCDs.
template<bool COMPACT>
__global__ __launch_bounds__(256, 4)
void k_body0_router(const bf16_t* __restrict__ xb, const bf16_t* __restrict__ W1t,
                    const float* __restrict__ bb1, bf16_t* __restrict__ hbuf,
                    const bf16_t* __restrict__ xlo,
                    const bf16_t* __restrict__ R1h, const bf16_t* __restrict__ R1l,
                    const float* __restrict__ Rb1, float* __restrict__ hr,
                    const int* __restrict__ idxl, const int* __restrict__ cntp,
                    int nbody)
{
  __shared__ __align__(16) bf16_t sm[16384];
  int cnt = NTOK;
  int mtA = NTOK >> 7;
  if (COMPACT) {
    cnt = *cntp;
    mtA = (cnt + 127) >> 7;
  }
  const int g = blockIdx.x;
  if (g < nbody) {
    int mt, nt;
    if (COMPACT) {
      if (g >= mtA * (DFF >> 7)) return;
      mt = g % mtA;
      nt = g / mtA;
    } else {
      remap_tile(g, mt, nt);
    }
    body_tile<0, false, false, 4, 4, COMPACT>(
        mt, nt, xb, W1t, bb1, DFF, HDIM, hbuf,
        nullptr, nullptr, nullptr, nullptr, nullptr,
        idxl, cnt, sm, sm + 8192);
  } else {
    const int g2 = g - nbody;
    int mt, nt;
    if (COMPACT) {
      if (g2 >= mtA * (RHID >> 7)) return;
      mt = g2 % mtA;
      nt = g2 / mtA;
    } else {
      remap_tile(g2, mt, nt);
    }
    router_tile<COMPACT>(mt, nt, xb, xlo, R1h, R1l, Rb1, hr, idxl, cnt,
                         sm, sm + 4096, sm + 8192, sm + 12288);
  }
}

// ---------------------------------------------------------------------------
// ACT: one wave per token, fp32 logit + exact halting update (in-place state).
// ---------------------------------------------------------------------------
__global__ void act_kernel(const float* __restrict__ Hr,
                           const float* __restrict__ rw2, const float* __restrict__ rb2,
                           float* __restrict__ cum_p, float* __restrict__ still_r,
                           float* __restrict__ wsum, float* __restrict__ wvec)
{
  const int t = blockIdx.x * 4 + (threadIdx.x >> 6);
  const int lane = threadIdx.x & 63;
  float s = 0.f;
#pragma unroll
  for (int j = 0; j < 8; ++j) {
    const int m = lane + j * 64;
    s += Hr[(size_t)t * RHID + m] * rw2[m];
  }
  for (int off = 32; off > 0; off >>= 1) s += __shfl_down(s, off, 64);
  if (lane == 0) {
    const float logit = s + rb2[0];
    const float p = 1.f / (1.f + expf(-logit));
    const float cum = cum_p[t];
    const float still = still_r[t];
    const float rem = fmaxf(1.f - cum, 0.f);
    const bool halt = (cum + p) >= 0.99f;
    const float w = (halt ? rem : p) * still;
    wvec[t] = w;
    wsum[t] += w;
    cum_p[t] = cum + w;
    if (halt) still_r[t] = 0.f;
  }
}

// ---------------------------------------------------------------------------
// Ordered survivor compaction: token-sorted idxl (sequential gathers) via
// single-block ballot/popc prefix scan. ~5 us.
// ---------------------------------------------------------------------------
__global__ void compact_kernel(const float* __restrict__ still,
                               int* __restrict__ idxl, int* __restrict__ cntp)
{
  __shared__ int wsumS[16];
  const int tid  = threadIdx.x;     // 0..1023
  const int w    = tid >> 6;
  const int lane = tid & 63;
  int base = 0;
  for (int c = 0; c < 8; ++c) {
    const int t = c * 1024 + tid;
    const bool f = still[t] > 0.f;
    const unsigned long long m = __ballot(f);
    if (lane == 0) wsumS[w] = __popcll(m);
    __syncthreads();
    int woff = 0, tot = 0;
#pragma unroll
    for (int i = 0; i < 16; ++i) {
      const int v = wsumS[i];
      if (i < w) woff += v;
      tot += v;
    }
    if (f) idxl[base + woff + __popcll(m & ((1ull << lane) - 1ull))] = t;
    base += tot;
    __syncthreads();
  }
  if (tid == 0) *cntp = base;
}

// ---------------------------------------------------------------------------
// Fused prep: Wb1/Wb2/Rw1 transposes + x->bf16 convert + ACT state init.
// ---------------------------------------------------------------------------
__device__ __forceinline__ void transpose_tile(
    const float* __restrict__ src, int srcld, int dstld,
    bf16_t* __restrict__ dst, bf16_t* __restrict__ dlo,
    int bx, int by, float* tile /* 32x33 */)
{
  const int tx = threadIdx.x & 31;
  const int ty = threadIdx.x >> 5;
#pragma unroll
  for (int l = 0; l < 4; ++l)
    tile[(ty + l * 8) * 33 + tx] = src[(size_t)(by * 32 + ty + l * 8) * srcld + bx * 32 + tx];
  __syncthreads();
#pragma unroll
  for (int l = 0; l < 4; ++l) {
    const int c = bx * 32 + ty + l * 8;
    const int r = by * 32 + tx;
    const float v = tile[tx * 33 + ty + l * 8];
    const bf16_t hi = (bf16_t)v;
    dst[(size_t)c * dstld + r] = hi;
    if (dlo) dlo[(size_t)c * dstld + r] = (bf16_t)(v - (float)hi);
  }
}

__global__ void prep_kernel(const float* __restrict__ x,
                            const float* __restrict__ Wb1,
                            const float* __restrict__ Wb2,
                            const float* __restrict__ Rw1,
                            bf16_t* __restrict__ xb,
                            bf16_t* __restrict__ W1t, bf16_t* __restrict__ W2t,
                            bf16_t* __restrict__ R1h, bf16_t* __restrict__ R1l,
                            float* __restrict__ cum0, float* __restrict__ stil0,
                            float* __restrict__ wsum0, int* __restrict__ cntp)
{
  __shared__ float tile[32 * 33];
  const int g = blockIdx.x;
  if (g < 4096) {                       // Wb1 (H x DFF) -> W1t (DFF x H)
    transpose_tile(Wb1, DFF, HDIM, W1t, nullptr, g & 127, g >> 7, tile);
  } else if (g < 8192) {                // Wb2 (DFF x H) -> W2t (H x DFF)
    const int g2 = g - 4096;
    transpose_tile(Wb2, HDIM, DFF, W2t, nullptr, g2 & 31, g2 >> 5, tile);
  } else if (g < 9728) {                // Rw1[i] (first 1024 of 1025 rows) -> hi/lo
    const int g3 = g - 8192;
    const int i  = g3 >> 9;
    const int r  = g3 & 511;
    transpose_tile(Rw1 + (size_t)i * 1025 * RHID, RHID, HDIM,
                   R1h + (size_t)i * RHID * HDIM, R1l + (size_t)i * RHID * HDIM,
                   r & 15, r >> 4, tile);
  } else if (g < 17920) {               // x fp32 -> xb bf16 (vectorized)
    const int i = (g - 9728) * 256 + threadIdx.x;
    const float4 v = ((const float4*)x)[i];
    bf16x4 hb;
    hb[0] = (bf16_t)v.x; hb[1] = (bf16_t)v.y; hb[2] = (bf16_t)v.z; hb[3] = (bf16_t)v.w;
    ((bf16x4*)xb)[i] = hb;
  } else {                              // ACT state init
    const int t = (g - 17920) * 256 + threadIdx.x;
    cum0[t] = 0.f; stil0[t] = 1.f; wsum0[t] = 1.f;
    if (t == 0) *cntp = 0;
  }
}

__global__ void finalize_kernel(const float* __restrict__ wsum, float* __restrict__ out)
{
  __shared__ float red[256];
  float s = 0.f;
  for (int i = threadIdx.x; i < NTOK; i += 256) s += wsum[i];
  red[threadIdx.x] = s;
  __syncthreads();
  for (int o = 128; o > 0; o >>= 1) {
    if (threadIdx.x < o) red[threadIdx.x] += red[threadIdx.x + o];
    __syncthreads();
  }
  if (threadIdx.x == 0) {
    const float avg = red[0] / (float)NTOK;
    float d = avg - 2.5f;
    d = fmaxf(d, 0.f);
    out[0] = 0.01f * d * d;
  }
}

extern "C" void kernel_launch(void* const* d_in, const int* in_sizes, int n_in,
                              void* d_out, int out_size, void* d_ws, size_t ws_size,
                              hipStream_t stream) {
  const float* x   = (const float*)d_in[0];
  const float* Wb1 = (const float*)d_in[1];
  const float* bb1 = (const float*)d_in[2];
  const float* Wb2 = (const float*)d_in[3];
  const float* bb2 = (const float*)d_in[4];
  const float* Rw1 = (const float*)d_in[5];  // (3, 1025, 512)
  const float* Rb1 = (const float*)d_in[6];  // (3, 512)
  const float* Rw2 = (const float*)d_in[7];  // (3, 512)
  const float* Rb2 = (const float*)d_in[8];  // (3,)
  float* out = (float*)d_out;

  char* ws = (char*)d_ws;
  size_t off = 0;
  auto carve = [&](size_t bytes) -> void* {
    void* p = ws + off;
    off += (bytes + 255) & ~(size_t)255;
    return p;
  };
  bf16_t* xb   = (bf16_t*)carve((size_t)NTOK * HDIM * 2);
  bf16_t* xlo  = (bf16_t*)carve((size_t)NTOK * HDIM * 2);
  bf16_t* hbuf = (bf16_t*)carve((size_t)NTOK * DFF * 2);
  bf16_t* W1t  = (bf16_t*)carve((size_t)HDIM * DFF * 2);
  bf16_t* W2t  = (bf16_t*)carve((size_t)HDIM * DFF * 2);
  bf16_t* R1h  = (bf16_t*)carve((size_t)3 * RHID * HDIM * 2);
  bf16_t* R1l  = (bf16_t*)carve((size_t)3 * RHID * HDIM * 2);
  float*  hr   = (float*)carve((size_t)NTOK * RHID * 4);
  float*  cum  = (float*)carve((size_t)NTOK * 4);
  float*  stil = (float*)carve((size_t)NTOK * 4);
  float*  wsum = (float*)carve((size_t)NTOK * 4);
  float*  wvec = (float*)carve((size_t)NTOK * 4);
  int*    idxl = (int*)carve((size_t)NTOK * 4);
  int*    cntp = (int*)carve(256);

  prep_kernel<<<17952, 256, 0, stream>>>(x, Wb1, Wb2, Rw1, xb, W1t, W2t,
                                         R1h, R1l, cum, stil, wsum, cntp);

  // mandatory first body: x = body(x); x kept as hi/lo bf16 pair
  k_body0_router<false><<<2048, 256, 0, stream>>>(
      xb, W1t, bb1, hbuf, xlo, nullptr, nullptr, nullptr, nullptr,
      idxl, cntp, 2048);
  k_gemm<1, false, false, false><<<512, 256, 0, stream>>>(
      hbuf, W2t, bb2, HDIM, DFF, nullptr, xb, xlo, nullptr, nullptr,
      idxl, cntp);

  // i = 0: full
  k_body0_router<false><<<2048 + 256, 256, 0, stream>>>(
      xb, W1t, bb1, hbuf, xlo, R1h, R1l, Rb1, hr, idxl, cntp, 2048);
  act_kernel<<<2048, 256, 0, stream>>>(hr, Rw2, Rb2, cum, stil, wsum, wvec);
  k_gemm<2, false, false, false><<<512, 256, 0, stream>>>(
      hbuf, W2t, bb2, HDIM, DFF, nullptr, xb, xlo, wvec, nullptr,
      idxl, cntp);

  // i = 1: full; afterwards still_r marks survivors of iterations 0+1
  k_body0_router<false><<<2048 + 256, 256, 0, stream>>>(
      xb, W1t, bb1, hbuf, xlo,
      R1h + (size_t)RHID * HDIM, R1l + (size_t)RHID * HDIM,
      Rb1 + RHID, hr, idxl, cntp, 2048);
  act_kernel<<<2048, 256, 0, stream>>>(hr, Rw2 + RHID, Rb2 + 1,
                                       cum, stil, wsum, wvec);
  compact_kernel<<<1, 1024, 0, stream>>>(stil, idxl, cntp);
  // i=1 blend; HALTW writes final Xout for halted tokens (== w=0 blend)
  k_gemm<2, false, true, false><<<512, 256, 0, stream>>>(
      hbuf, W2t, bb2, HDIM, DFF, out, xb, xlo, wvec, stil, idxl, cntp);

  // i = 2: compacted (survivors only; active tiles contiguous across XCDs)
  k_body0_router<true><<<2048 + 256, 256, 0, stream>>>(
      xb, W1t, bb1, hbuf, xlo,
      R1h + (size_t)2 * RHID * HDIM, R1l + (size_t)2 * RHID * HDIM,
      Rb1 + 2 * RHID, hr, idxl, cntp, 2048);
  act_kernel<<<2048, 256, 0, stream>>>(hr, Rw2 + 2 * RHID, Rb2 + 2,
                                       cum, stil, wsum, wvec);
  k_gemm<2, true, false, true><<<512, 256, 0, stream>>>(
      hbuf, W2t, bb2, HDIM, DFF, out, xb, xlo, wvec, nullptr, idxl, cntp);

  finalize_kernel<<<1, 256, 0, stream>>>(wsum, out + (size_t)NTOK * HDIM);
  (void)in_sizes; (void)n_in; (void)out_size; (void)ws_size;
}

// Round 11
// 819.152 us; speedup vs baseline: 1.1321x; 1.0154x over previous
//
#include <hip/hip_runtime.h>
#include <hip/hip_bf16.h>
#include <math.h>

typedef __bf16 bf16_t;
typedef __attribute__((ext_vector_type(8))) __bf16 bf16x8;
typedef __attribute__((ext_vector_type(4))) __bf16 bf16x4;
typedef __attribute__((ext_vector_type(4))) float f32x4;

#define NTOK 8192   // B*T
#define HDIM 1024
#define DFF  4096
#define RHID 512

__device__ __forceinline__ float gelu_exact(float v) {
  return 0.5f * v * (1.0f + erff(v * 0.70710678118654752f));
}

// tanh-form gelu via sigmoid; max abs err ~3e-4 (noise vs bf16 quantization).
__device__ __forceinline__ float gelu_fast(float v) {
  const float g = 1.5957691216057308f * (v + 0.044715f * v * v * v);
  return v / (1.0f + __expf(-g));
}

__device__ __forceinline__ void async_cp16(void* lds, const void* g) {
  __builtin_amdgcn_global_load_lds(
      (__attribute__((address_space(1))) void*)g,
      (__attribute__((address_space(3))) void*)lds, 16, 0, 0);
}

// XCD-aware remap for FULL launches: blocks round-robin XCDs on g&7; each
// XCD owns an 8-mt strip (A-strip L2-resident), mt fastest for B reuse.
__device__ __forceinline__ void remap_tile(int g, int& mt, int& nt) {
  mt = ((g & 7) << 3) | ((g >> 3) & 7);
  nt = g >> 6;
}

// ---------------------------------------------------------------------------
// GEMM tile, BK=64 single-buffered (r0-proven loop). 4 waves 2x2.
// 16x16x32 MFMA; quad-based LDS read (2-way banks = free, m136).
// [r9 lesson: 32x32 fragment reads are structurally 4-way bank-conflicted
//  under global_load_lds's linear 128B-pitch LDS — do not swap shapes here.]
// MODE 0: h = bf16(gelu_fast(C)) -> Hout.    [COMPACT: A rows gathered]
// MODE 1: x = C; hi/lo bf16 split.
// MODE 2: x = w*C + (1-w)*(hi+lo); hi/lo stored.
//   WRITE_OUT: also Xout = v (final iter, survivors).
//   HALTW: for rows with Stil[tok]==0, Xout = (float)hi+(float)lo — exactly
//          the baseline's later w=0 blend output (bit-identical).
//   COMPACT (MODE2): A rows compact-direct; Xb/Xlo/Wmix/Xout token-indexed
//          via ordered idxl; stores guarded to gm < cnt.
// ---------------------------------------------------------------------------
template<int MODE, bool WRITE_OUT, bool HALTW, int WM, int WN, bool COMPACT>
__device__ __forceinline__ void body_tile(
    int mt, int nt,
    const bf16_t* __restrict__ A, const bf16_t* __restrict__ Bt,
    const float* __restrict__ bias, int N, int K,
    bf16_t* __restrict__ Hout, float* __restrict__ Xout,
    bf16_t* __restrict__ Xb, bf16_t* __restrict__ Xlo,
    const float* __restrict__ Wmix, const float* __restrict__ Stil,
    const int* __restrict__ idxl, int cnt,
    bf16_t* As, bf16_t* Bs)
{
  constexpr int BM  = WM * 32;
  constexpr int BN  = WN * 32;
  constexpr int ACH = BM / 32;
  constexpr int BCH = BN / 32;
  const int tid  = threadIdx.x;
  const int lane = tid & 63;
  const int wv   = tid >> 6;
  const int wm   = wv >> 1;
  const int wn   = wv & 1;
  const int lr   = lane & 15;
  const int quad = lane >> 4;
  const int m0 = mt * BM;
  const int n0 = nt * BN;

  f32x4 acc[WM][WN];
#pragma unroll
  for (int i = 0; i < WM; ++i)
#pragma unroll
    for (int j = 0; j < WN; ++j)
      acc[i][j] = (f32x4){0.f, 0.f, 0.f, 0.f};

  const int c   = tid;
  const int row = c >> 3;
  const int ks  = (((c & 7) - (row & 7)) & 7) * 8;
  const bf16_t* Ag[ACH];
#pragma unroll
  for (int t = 0; t < ACH; ++t) {
    int rr = m0 + row + 32 * t;
    if (COMPACT && MODE == 0) rr = idxl[rr < cnt ? rr : cnt - 1];
    Ag[t] = A + (size_t)rr * K + ks;
  }
  const bf16_t* Bgb = Bt + (size_t)(n0 + row) * K + ks;
  char* lAb = (char*)As + c * 16;
  char* lBb = (char*)Bs + c * 16;

  for (int kb = 0; kb < K; kb += 64) {
    __syncthreads();
#pragma unroll
    for (int t = 0; t < ACH; ++t)
      async_cp16(lAb + 4096 * t, Ag[t] + kb);
#pragma unroll
    for (int t = 0; t < BCH; ++t)
      async_cp16(lBb + 4096 * t, Bgb + (size_t)32 * t * K + kb);
    __syncthreads();
#pragma unroll
    for (int kk = 0; kk < 2; ++kk) {
      const int kg = kk * 4 + quad;
      bf16x8 af[WM], bfr[WN];
#pragma unroll
      for (int i = 0; i < WM; ++i) {
        const int ra = wm * (WM * 16) + i * 16 + lr;
        af[i] = *(const bf16x8*)&As[ra * 64 + ((kg + ra) & 7) * 8];
      }
#pragma unroll
      for (int j = 0; j < WN; ++j) {
        const int rb = wn * (WN * 16) + j * 16 + lr;
        bfr[j] = *(const bf16x8*)&Bs[rb * 64 + ((kg + rb) & 7) * 8];
      }
#pragma unroll
      for (int i = 0; i < WM; ++i)
#pragma unroll
        for (int j = 0; j < WN; ++j)
          acc[i][j] = __builtin_amdgcn_mfma_f32_16x16x32_bf16(af[i], bfr[j], acc[i][j], 0, 0, 0);
    }
  }

#pragma unroll
  for (int i = 0; i < WM; ++i) {
#pragma unroll
    for (int r = 0; r < 4; ++r) {
      const int gm = m0 + wm * (WM * 16) + i * 16 + quad * 4 + r;
      bool act_row = true;
      int tok = gm;
      if (COMPACT && MODE == 2) {
        act_row = gm < cnt;
        tok = idxl[act_row ? gm : cnt - 1];
      }
      float wmix = 0.f, onemw = 0.f, st = 1.f;
      if (MODE == 2) {
        wmix = Wmix[tok]; onemw = 1.f - wmix;
        if (HALTW) st = Stil[tok];
      }
#pragma unroll
      for (int j = 0; j < WN; ++j) {
        const int gn = n0 + wn * (WN * 16) + j * 16 + lr;
        float v = acc[i][j][r] + bias[gn];
        if (MODE == 0) {
          Hout[(size_t)gm * N + gn] = (bf16_t)gelu_fast(v);
        } else {
          const size_t idx = (size_t)tok * N + gn;
          if (MODE == 2) {
            const float xold = (float)Xb[idx] + (float)Xlo[idx];
            v = wmix * v + onemw * xold;
          }
          if (act_row) {
            const bf16_t hi = (bf16_t)v;
            const bf16_t lo = (bf16_t)(v - (float)hi);
            Xb[idx]  = hi;
            Xlo[idx] = lo;
            if (WRITE_OUT) Xout[idx] = v;
            if (HALTW && st == 0.f) Xout[idx] = (float)hi + (float)lo;
          }
        }
      }
    }
  }
}

// ---------------------------------------------------------------------------
// Router tile (hi/lo split ~fp32), BK=32 single-buffered, 32KB LDS.
// COMPACT: A rows (xb/xlo) gathered via ordered idxl; Hr scattered + guarded.
// ---------------------------------------------------------------------------
template<bool COMPACT>
__device__ __forceinline__ void router_tile(
    int mt, int nt,
    const bf16_t* __restrict__ Ah, const bf16_t* __restrict__ Al,
    const bf16_t* __restrict__ Bh, const bf16_t* __restrict__ Bl,
    const float* __restrict__ bias, float* __restrict__ Hr,
    const int* __restrict__ idxl, int cnt,
    bf16_t* Ahs, bf16_t* Als, bf16_t* Bhs, bf16_t* Bls)
{
  const int K = HDIM, N = RHID;
  const int tid  = threadIdx.x;
  const int lane = tid & 63;
  const int wv   = tid >> 6;
  const int wm   = wv >> 1;
  const int wn   = wv & 1;
  const int lr   = lane & 15;
  const int quad = lane >> 4;
  const int m0 = mt * 128;
  const int n0 = nt * 128;

  f32x4 acc[4][4];
#pragma unroll
  for (int i = 0; i < 4; ++i)
#pragma unroll
    for (int j = 0; j < 4; ++j)
      acc[i][j] = (f32x4){0.f, 0.f, 0.f, 0.f};

  const int c0 = tid;
  const int c1 = tid + 256;
  const int r0 = c0 >> 2, r1 = c1 >> 2;
  const int ks0 = ((c0 ^ r0) & 3) * 8;
  const int ks1 = ((c1 ^ r1) & 3) * 8;
  int tr0 = m0 + r0, tr1 = m0 + r1;
  if (COMPACT) {
    tr0 = idxl[tr0 < cnt ? tr0 : cnt - 1];
    tr1 = idxl[tr1 < cnt ? tr1 : cnt - 1];
  }
  const size_t aoff0 = (size_t)tr0 * K + ks0;
  const size_t aoff1 = (size_t)tr1 * K + ks1;
  const size_t boff0 = (size_t)(n0 + r0) * K + ks0;
  const size_t boff1 = (size_t)(n0 + r1) * K + ks1;
  const int sw = ((quad ^ lr) & 3) * 8;

  for (int k0 = 0; k0 < K; k0 += 32) {
    __syncthreads();
    async_cp16((char*)Ahs + c0 * 16, Ah + aoff0 + k0);
    async_cp16((char*)Ahs + c1 * 16, Ah + aoff1 + k0);
    async_cp16((char*)Als + c0 * 16, Al + aoff0 + k0);
    async_cp16((char*)Als + c1 * 16, Al + aoff1 + k0);
    async_cp16((char*)Bhs + c0 * 16, Bh + boff0 + k0);
    async_cp16((char*)Bhs + c1 * 16, Bh + boff1 + k0);
    async_cp16((char*)Bls + c0 * 16, Bl + boff0 + k0);
    async_cp16((char*)Bls + c1 * 16, Bl + boff1 + k0);
    __syncthreads();
    bf16x8 ah[4], al[4], bh[4], bl[4];
#pragma unroll
    for (int i = 0; i < 4; ++i) {
      const int ao = (wm * 64 + i * 16 + lr) * 32 + sw;
      ah[i] = *(const bf16x8*)&Ahs[ao];
      al[i] = *(const bf16x8*)&Als[ao];
    }
#pragma unroll
    for (int j = 0; j < 4; ++j) {
      const int bo = (wn * 64 + j * 16 + lr) * 32 + sw;
      bh[j] = *(const bf16x8*)&Bhs[bo];
      bl[j] = *(const bf16x8*)&Bls[bo];
    }
#pragma unroll
    for (int i = 0; i < 4; ++i)
#pragma unroll
      for (int j = 0; j < 4; ++j) {
        acc[i][j] = __builtin_amdgcn_mfma_f32_16x16x32_bf16(ah[i], bh[j], acc[i][j], 0, 0, 0);
        acc[i][j] = __builtin_amdgcn_mfma_f32_16x16x32_bf16(al[i], bh[j], acc[i][j], 0, 0, 0);
        acc[i][j] = __builtin_amdgcn_mfma_f32_16x16x32_bf16(ah[i], bl[j], acc[i][j], 0, 0, 0);
      }
  }

#pragma unroll
  for (int i = 0; i < 4; ++i)
#pragma unroll
    for (int r = 0; r < 4; ++r) {
      const int gm = m0 + wm * 64 + i * 16 + quad * 4 + r;
      bool act_row = true;
      int tok = gm;
      if (COMPACT) {
        act_row = gm < cnt;
        tok = idxl[act_row ? gm : cnt - 1];
      }
#pragma unroll
      for (int j = 0; j < 4; ++j) {
        const int gn = n0 + wn * 64 + j * 16 + lr;
        if (act_row) Hr[(size_t)tok * N + gn] = gelu_exact(acc[i][j][r] + bias[gn]);
      }
    }
}

// MODE1/MODE2 standalone GEMM, 128x128 tiles, 32KB LDS.
// COMPACT: active tiles remapped to CONTIGUOUS blockIdx (all XCDs busy).
template<int MODE, bool WRITE_OUT, bool HALTW, bool COMPACT>
__global__ __launch_bounds__(256, 4)
void k_gemm(const bf16_t* __restrict__ A, const bf16_t* __restrict__ Bt,
            const float* __restrict__ bias, int N, int K,
            float* __restrict__ Xout, bf16_t* __restrict__ Xb,
            bf16_t* __restrict__ Xlo, const float* __restrict__ Wmix,
            const float* __restrict__ Stil,
            const int* __restrict__ idxl, const int* __restrict__ cntp)
{
  __shared__ __align__(16) bf16_t sm[16384];
  int cnt = NTOK;
  int mt, nt;
  if (COMPACT) {
    cnt = *cntp;
    const int mtA = (cnt + 127) >> 7;
    if ((int)blockIdx.x >= mtA * (N >> 7)) return;
    mt = blockIdx.x % mtA;
    nt = blockIdx.x / mtA;
  } else {
    remap_tile(blockIdx.x, mt, nt);
  }
  body_tile<MODE, WRITE_OUT, HALTW, 4, 4, COMPACT>(
      mt, nt, A, Bt, bias, N, K, nullptr, Xout, Xb, Xlo, Wmix, Stil,
      idxl, cnt, sm, sm + 8192);
}

// MODE0 body (2048 tiles) + router (256 tiles), ROUTER-FIRST dispatch order:
// g < nrouter -> router tile (3x heavier than a body tile: K=1024, 3 MFMA
// chains + fp32 stores). Longest-job-first kills the all-router tail round
// of the previous layout (2304 = 9 exact CU-rounds; last was all-router).
// nrouter % 8 == 0 keeps the body XCD round-robin ((g-nrouter)&7 == g&7).
// COMPACT: active tiles contiguous so work round-robins XCDs.
template<bool COMPACT>
__global__ __launch_bounds__(256, 4)
void k_body0_router(const bf16_t* __restrict__ xb, const bf16_t* __restrict__ W1t,
                    const float* __restrict__ bb1, bf16_t* __restrict__ hbuf,
                    const bf16_t* __restrict__ xlo,
                    const bf16_t* __restrict__ R1h, const bf16_t* __restrict__ R1l,
                    const float* __restrict__ Rb1, float* __restrict__ hr,
                    const int* __restrict__ idxl, const int* __restrict__ cntp,
                    int nrouter)
{
  __shared__ __align__(16) bf16_t sm[16384];
  int cnt = NTOK;
  int mtA = NTOK >> 7;
  if (COMPACT) {
    cnt = *cntp;
    mtA = (cnt + 127) >> 7;
  }
  const int g = blockIdx.x;
  if (g >= nrouter) {
    const int gb = g - nrouter;
    int mt, nt;
    if (COMPACT) {
      if (gb >= mtA * (DFF >> 7)) return;
      mt = gb % mtA;
      nt = gb / mtA;
    } else {
      remap_tile(gb, mt, nt);
    }
    body_tile<0, false, false, 4, 4, COMPACT>(
        mt, nt, xb, W1t, bb1, DFF, HDIM, hbuf,
        nullptr, nullptr, nullptr, nullptr, nullptr,
        idxl, cnt, sm, sm + 8192);
  } else {
    int mt, nt;
    if (COMPACT) {
      if (g >= mtA * (RHID >> 7)) return;
      mt = g % mtA;
      nt = g / mtA;
    } else {
      remap_tile(g, mt, nt);
    }
    router_tile<COMPACT>(mt, nt, xb, xlo, R1h, R1l, Rb1, hr, idxl, cnt,
                         sm, sm + 4096, sm + 8192, sm + 12288);
  }
}

// ---------------------------------------------------------------------------
// ACT: one wave per token, fp32 logit + exact halting update (in-place state).
// ---------------------------------------------------------------------------
__global__ void act_kernel(const float* __restrict__ Hr,
                           const float* __restrict__ rw2, const float* __restrict__ rb2,
                           float* __restrict__ cum_p, float* __restrict__ still_r,
                           float* __restrict__ wsum, float* __restrict__ wvec)
{
  const int t = blockIdx.x * 4 + (threadIdx.x >> 6);
  const int lane = threadIdx.x & 63;
  float s = 0.f;
#pragma unroll
  for (int j = 0; j < 8; ++j) {
    const int m = lane + j * 64;
    s += Hr[(size_t)t * RHID + m] * rw2[m];
  }
  for (int off = 32; off > 0; off >>= 1) s += __shfl_down(s, off, 64);
  if (lane == 0) {
    const float logit = s + rb2[0];
    const float p = 1.f / (1.f + expf(-logit));
    const float cum = cum_p[t];
    const float still = still_r[t];
    const float rem = fmaxf(1.f - cum, 0.f);
    const bool halt = (cum + p) >= 0.99f;
    const float w = (halt ? rem : p) * still;
    wvec[t] = w;
    wsum[t] += w;
    cum_p[t] = cum + w;
    if (halt) still_r[t] = 0.f;
  }
}

// ---------------------------------------------------------------------------
// Ordered survivor compaction: token-sorted idxl (sequential gathers) via
// single-block ballot/popc prefix scan. ~5 us.
// ---------------------------------------------------------------------------
__global__ void compact_kernel(const float* __restrict__ still,
                               int* __restrict__ idxl, int* __restrict__ cntp)
{
  __shared__ int wsumS[16];
  const int tid  = threadIdx.x;     // 0..1023
  const int w    = tid >> 6;
  const int lane = tid & 63;
  int base = 0;
  for (int c = 0; c < 8; ++c) {
    const int t = c * 1024 + tid;
    const bool f = still[t] > 0.f;
    const unsigned long long m = __ballot(f);
    if (lane == 0) wsumS[w] = __popcll(m);
    __syncthreads();
    int woff = 0, tot = 0;
#pragma unroll
    for (int i = 0; i < 16; ++i) {
      const int v = wsumS[i];
      if (i < w) woff += v;
      tot += v;
    }
    if (f) idxl[base + woff + __popcll(m & ((1ull << lane) - 1ull))] = t;
    base += tot;
    __syncthreads();
  }
  if (tid == 0) *cntp = base;
}

// ---------------------------------------------------------------------------
// Fused prep: Wb1/Wb2/Rw1 transposes + x->bf16 convert + ACT state init.
// ---------------------------------------------------------------------------
__device__ __forceinline__ void transpose_tile(
    const float* __restrict__ src, int srcld, int dstld,
    bf16_t* __restrict__ dst, bf16_t* __restrict__ dlo,
    int bx, int by, float* tile /* 32x33 */)
{
  const int tx = threadIdx.x & 31;
  const int ty = threadIdx.x >> 5;
#pragma unroll
  for (int l = 0; l < 4; ++l)
    tile[(ty + l * 8) * 33 + tx] = src[(size_t)(by * 32 + ty + l * 8) * srcld + bx * 32 + tx];
  __syncthreads();
#pragma unroll
  for (int l = 0; l < 4; ++l) {
    const int c = bx * 32 + ty + l * 8;
    const int r = by * 32 + tx;
    const float v = tile[tx * 33 + ty + l * 8];
    const bf16_t hi = (bf16_t)v;
    dst[(size_t)c * dstld + r] = hi;
    if (dlo) dlo[(size_t)c * dstld + r] = (bf16_t)(v - (float)hi);
  }
}

__global__ void prep_kernel(const float* __restrict__ x,
                            const float* __restrict__ Wb1,
                            const float* __restrict__ Wb2,
                            const float* __restrict__ Rw1,
                            bf16_t* __restrict__ xb,
                            bf16_t* __restrict__ W1t, bf16_t* __restrict__ W2t,
                            bf16_t* __restrict__ R1h, bf16_t* __restrict__ R1l,
                            float* __restrict__ cum0, float* __restrict__ stil0,
                            float* __restrict__ wsum0, int* __restrict__ cntp)
{
  __shared__ float tile[32 * 33];
  const int g = blockIdx.x;
  if (g < 4096) {                       // Wb1 (H x DFF) -> W1t (DFF x H)
    transpose_tile(Wb1, DFF, HDIM, W1t, nullptr, g & 127, g >> 7, tile);
  } else if (g < 8192) {                // Wb2 (DFF x H) -> W2t (H x DFF)
    const int g2 = g - 4096;
    transpose_tile(Wb2, HDIM, DFF, W2t, nullptr, g2 & 31, g2 >> 5, tile);
  } else if (g < 9728) {                // Rw1[i] (first 1024 of 1025 rows) -> hi/lo
    const int g3 = g - 8192;
    const int i  = g3 >> 9;
    const int r  = g3 & 511;
    transpose_tile(Rw1 + (size_t)i * 1025 * RHID, RHID, HDIM,
                   R1h + (size_t)i * RHID * HDIM, R1l + (size_t)i * RHID * HDIM,
                   r & 15, r >> 4, tile);
  } else if (g < 17920) {               // x fp32 -> xb bf16 (vectorized)
    const int i = (g - 9728) * 256 + threadIdx.x;
    const float4 v = ((const float4*)x)[i];
    bf16x4 hb;
    hb[0] = (bf16_t)v.x; hb[1] = (bf16_t)v.y; hb[2] = (bf16_t)v.z; hb[3] = (bf16_t)v.w;
    ((bf16x4*)xb)[i] = hb;
  } else {                              // ACT state init
    const int t = (g - 17920) * 256 + threadIdx.x;
    cum0[t] = 0.f; stil0[t] = 1.f; wsum0[t] = 1.f;
    if (t == 0) *cntp = 0;
  }
}

__global__ void finalize_kernel(const float* __restrict__ wsum, float* __restrict__ out)
{
  __shared__ float red[256];
  float s = 0.f;
  for (int i = threadIdx.x; i < NTOK; i += 256) s += wsum[i];
  red[threadIdx.x] = s;
  __syncthreads();
  for (int o = 128; o > 0; o >>= 1) {
    if (threadIdx.x < o) red[threadIdx.x] += red[threadIdx.x + o];
    __syncthreads();
  }
  if (threadIdx.x == 0) {
    const float avg = red[0] / (float)NTOK;
    float d = avg - 2.5f;
    d = fmaxf(d, 0.f);
    out[0] = 0.01f * d * d;
  }
}

extern "C" void kernel_launch(void* const* d_in, const int* in_sizes, int n_in,
                              void* d_out, int out_size, void* d_ws, size_t ws_size,
                              hipStream_t stream) {
  const float* x   = (const float*)d_in[0];
  const float* Wb1 = (const float*)d_in[1];
  const float* bb1 = (const float*)d_in[2];
  const float* Wb2 = (const float*)d_in[3];
  const float* bb2 = (const float*)d_in[4];
  const float* Rw1 = (const float*)d_in[5];  // (3, 1025, 512)
  const float* Rb1 = (const float*)d_in[6];  // (3, 512)
  const float* Rw2 = (const float*)d_in[7];  // (3, 512)
  const float* Rb2 = (const float*)d_in[8];  // (3,)
  float* out = (float*)d_out;

  char* ws = (char*)d_ws;
  size_t off = 0;
  auto carve = [&](size_t bytes) -> void* {
    void* p = ws + off;
    off += (bytes + 255) & ~(size_t)255;
    return p;
  };
  bf16_t* xb   = (bf16_t*)carve((size_t)NTOK * HDIM * 2);
  bf16_t* xlo  = (bf16_t*)carve((size_t)NTOK * HDIM * 2);
  bf16_t* hbuf = (bf16_t*)carve((size_t)NTOK * DFF * 2);
  bf16_t* W1t  = (bf16_t*)carve((size_t)HDIM * DFF * 2);
  bf16_t* W2t  = (bf16_t*)carve((size_t)HDIM * DFF * 2);
  bf16_t* R1h  = (bf16_t*)carve((size_t)3 * RHID * HDIM * 2);
  bf16_t* R1l  = (bf16_t*)carve((size_t)3 * RHID * HDIM * 2);
  float*  hr   = (float*)carve((size_t)NTOK * RHID * 4);
  float*  cum  = (float*)carve((size_t)NTOK * 4);
  float*  stil = (float*)carve((size_t)NTOK * 4);
  float*  wsum = (float*)carve((size_t)NTOK * 4);
  float*  wvec = (float*)carve((size_t)NTOK * 4);
  int*    idxl = (int*)carve((size_t)NTOK * 4);
  int*    cntp = (int*)carve(256);

  prep_kernel<<<17952, 256, 0, stream>>>(x, Wb1, Wb2, Rw1, xb, W1t, W2t,
                                         R1h, R1l, cum, stil, wsum, cntp);

  // mandatory first body: x = body(x); x kept as hi/lo bf16 pair
  k_body0_router<false><<<2048, 256, 0, stream>>>(
      xb, W1t, bb1, hbuf, xlo, nullptr, nullptr, nullptr, nullptr,
      idxl, cntp, 0);
  k_gemm<1, false, false, false><<<512, 256, 0, stream>>>(
      hbuf, W2t, bb2, HDIM, DFF, nullptr, xb, xlo, nullptr, nullptr,
      idxl, cntp);

  // i = 0: full (router tiles dispatched FIRST — longest-job-first)
  k_body0_router<false><<<2048 + 256, 256, 0, stream>>>(
      xb, W1t, bb1, hbuf, xlo, R1h, R1l, Rb1, hr, idxl, cntp, 256);
  act_kernel<<<2048, 256, 0, stream>>>(hr, Rw2, Rb2, cum, stil, wsum, wvec);
  k_gemm<2, false, false, false><<<512, 256, 0, stream>>>(
      hbuf, W2t, bb2, HDIM, DFF, nullptr, xb, xlo, wvec, nullptr,
      idxl, cntp);

  // i = 1: full; afterwards still_r marks survivors of iterations 0+1
  k_body0_router<false><<<2048 + 256, 256, 0, stream>>>(
      xb, W1t, bb1, hbuf, xlo,
      R1h + (size_t)RHID * HDIM, R1l + (size_t)RHID * HDIM,
      Rb1 + RHID, hr, idxl, cntp, 256);
  act_kernel<<<2048, 256, 0, stream>>>(hr, Rw2 + RHID, Rb2 + 1,
                                       cum, stil, wsum, wvec);
  compact_kernel<<<1, 1024, 0, stream>>>(stil, idxl, cntp);
  // i=1 blend; HALTW writes final Xout for halted tokens (== w=0 blend)
  k_gemm<2, false, true, false><<<512, 256, 0, stream>>>(
      hbuf, W2t, bb2, HDIM, DFF, out, xb, xlo, wvec, stil, idxl, cntp);

  // i = 2: compacted (survivors only; router-first, active tiles contiguous)
  k_body0_router<true><<<2048 + 256, 256, 0, stream>>>(
      xb, W1t, bb1, hbuf, xlo,
      R1h + (size_t)2 * RHID * HDIM, R1l + (size_t)2 * RHID * HDIM,
      Rb1 + 2 * RHID, hr, idxl, cntp, 256);
  act_kernel<<<2048, 256, 0, stream>>>(hr, Rw2 + 2 * RHID, Rb2 + 2,
                                       cum, stil, wsum, wvec);
  k_gemm<2, true, false, true><<<512, 256, 0, stream>>>(
      hbuf, W2t, bb2, HDIM, DFF, out, xb, xlo, wvec, nullptr, idxl, cntp);

  finalize_kernel<<<1, 256, 0, stream>>>(wsum, out + (size_t)NTOK * HDIM);
  (void)in_sizes; (void)n_in; (void)out_size; (void)ws_size;
}